// Round 1
// baseline (214.724 us; speedup 1.0000x reference)
//
#include <hip/hip_runtime.h>

// ---------------------------------------------------------------------------
// MemoryCausalSelfAttention for MI355X (gfx950).
// Pipeline: cvt(x,W)->bf16 ; copy mem_k1/k2 ; conv+LN compress mem_k3 ;
//           qkv GEMM (MFMA, fused scatter epilogue) ; flash attention (MFMA) ;
//           proj GEMM (MFMA) -> f32 out.
// Key insight: causal mask i>=j over concat axis => keys with index >=1024
// are never attended; effective key count is exactly 1024 per (b,h).
// ---------------------------------------------------------------------------

using u16    = unsigned short;
using bf16x8 = __attribute__((ext_vector_type(8))) __bf16;
using f32x4  = __attribute__((ext_vector_type(4))) float;
using u16x8  = __attribute__((ext_vector_type(8))) unsigned short;
using u16x4  = __attribute__((ext_vector_type(4))) unsigned short;

__device__ __forceinline__ u16 f2bf(float f) {
    union { float f; unsigned u; } v; v.f = f;
    unsigned r = v.u + 0x7FFFu + ((v.u >> 16) & 1u);   // RNE
    return (u16)(r >> 16);
}

// ---------------------------- elementwise f32->bf16 ------------------------
__global__ void cvt_f32_bf16(const float* __restrict__ src, u16* __restrict__ dst, int n4) {
    int i = blockIdx.x * blockDim.x + threadIdx.x;
    if (i >= n4) return;
    float4 f = reinterpret_cast<const float4*>(src)[i];
    u16x4 o; o[0] = f2bf(f.x); o[1] = f2bf(f.y); o[2] = f2bf(f.z); o[3] = f2bf(f.w);
    reinterpret_cast<u16x4*>(dst)[i] = o;
}

// ------------------- copy mem_k1/k2 (f32) into all_k (bf16) ----------------
// src: [64(bh)][L][64], dst rows [ro, ro+L) of [64][1024][64]
__global__ __launch_bounds__(64) void copy_mem_rows(const float* __restrict__ src,
                                                    u16* __restrict__ dst, int L, int ro) {
    int bh = blockIdx.y, t = blockIdx.x, d = threadIdx.x;
    float v = src[((size_t)bh * L + t) * 64 + d];
    dst[((size_t)bh * 1024 + ro + t) * 64 + d] = f2bf(v);
}

// --------- depthwise conv1d(k=2,s=2,pad=1) + LayerNorm(64) -> bf16 ---------
// src: [64(bh)][513][64]; out row t: w0*x[2t-1] + w1*x[2t] (x[-1]=0), then LN.
__global__ __launch_bounds__(64) void compress_ln(const float* __restrict__ src,
                                                  const float* __restrict__ w,
                                                  const float* __restrict__ g,
                                                  const float* __restrict__ bta,
                                                  u16* __restrict__ dst, int ro) {
    int bh = blockIdx.y, t = blockIdx.x, d = threadIdx.x;
    const float* seg = src + (size_t)bh * 513 * 64;
    float x0 = (t > 0) ? seg[(size_t)(2 * t - 1) * 64 + d] : 0.f;
    float x1 = seg[(size_t)(2 * t) * 64 + d];
    float y = w[2 * d] * x0 + w[2 * d + 1] * x1;
    float s = y;
    #pragma unroll
    for (int o = 32; o; o >>= 1) s += __shfl_xor(s, o);
    float mu = s * (1.f / 64.f);
    float dv = y - mu;
    float s2 = dv * dv;
    #pragma unroll
    for (int o = 32; o; o >>= 1) s2 += __shfl_xor(s2, o);
    float var = s2 * (1.f / 64.f);
    float out = dv * rsqrtf(var + 1e-5f) * g[d] + bta[d];
    dst[((size_t)bh * 1024 + ro + t) * 64 + d] = f2bf(out);
}

// --------------------------- GEMM: C = A * W^T + b -------------------------
// A [M][K] bf16, W [N][K] bf16. 64x64 tile, BK=64, 4 waves, 16x16x32 MFMA.
// mode 0: out f32 [M][N]. mode 1 (qkv): scatter q (scaled 1/8) to q_buf, and
// k/v tokens t<381 into all_k/all_v rows 643+t; head-major [bh][1024][64].
__global__ __launch_bounds__(256) void gemm_bt(const u16* __restrict__ A,
                                               const u16* __restrict__ Bw,
                                               const float* __restrict__ bias,
                                               int K, int N, int mode,
                                               float* __restrict__ outF,
                                               u16* __restrict__ q_buf,
                                               u16* __restrict__ all_k,
                                               u16* __restrict__ all_v) {
    __shared__ __align__(16) u16 Al[64][72];   // +8 pad: 2-way banks (free)
    __shared__ __align__(16) u16 Bl[64][72];
    const int tid = threadIdx.x;
    const int wv = tid >> 6, lane = tid & 63;
    const int lg = lane >> 4, lr = lane & 15;
    const int m0 = blockIdx.x * 64, n0 = blockIdx.y * 64;
    f32x4 acc[4] = {};
    const int rr = tid >> 3, cc = (tid & 7) * 8;
    for (int kt = 0; kt < K; kt += 64) {
        u16x8 a0 = *(const u16x8*)&A[(size_t)(m0 + rr) * K + kt + cc];
        u16x8 a1 = *(const u16x8*)&A[(size_t)(m0 + rr + 32) * K + kt + cc];
        u16x8 b0 = *(const u16x8*)&Bw[(size_t)(n0 + rr) * K + kt + cc];
        u16x8 b1 = *(const u16x8*)&Bw[(size_t)(n0 + rr + 32) * K + kt + cc];
        __syncthreads();
        *(u16x8*)&Al[rr][cc] = a0;
        *(u16x8*)&Al[rr + 32][cc] = a1;
        *(u16x8*)&Bl[rr][cc] = b0;
        *(u16x8*)&Bl[rr + 32][cc] = b1;
        __syncthreads();
        #pragma unroll
        for (int dh = 0; dh < 2; ++dh) {
            bf16x8 af = *(const bf16x8*)&Al[wv * 16 + lr][dh * 32 + lg * 8];
            #pragma unroll
            for (int nt = 0; nt < 4; ++nt) {
                bf16x8 bfr = *(const bf16x8*)&Bl[nt * 16 + lr][dh * 32 + lg * 8];
                acc[nt] = __builtin_amdgcn_mfma_f32_16x16x32_bf16(af, bfr, acc[nt], 0, 0, 0);
            }
        }
    }
    #pragma unroll
    for (int nt = 0; nt < 4; ++nt) {
        #pragma unroll
        for (int r = 0; r < 4; ++r) {
            int m = m0 + wv * 16 + lg * 4 + r;        // D row = (lane>>4)*4+reg
            int n = n0 + nt * 16 + lr;                // D col = lane&15
            float v = acc[nt][r] + bias[n];
            if (mode == 0) {
                outF[(size_t)m * N + n] = v;
            } else {
                int which = n >> 10, c = n & 1023, h = c >> 6, d = c & 63;
                int b = m >> 10, t = m & 1023;
                int bh = b * 16 + h;
                if (which == 0) {
                    q_buf[((size_t)bh * 1024 + t) * 64 + d] = f2bf(v * 0.125f);
                } else if (t < 381) {  // concat col 643+t must be <=1023
                    u16* dst = (which == 1) ? all_k : all_v;
                    dst[((size_t)bh * 1024 + 643 + t) * 64 + d] = f2bf(v);
                }
            }
        }
    }
}

// ------------------------------- attention ---------------------------------
// 1 wave / block, 16 queries. S^T = K·Q^T via mfma(A=K,B=Q^T): per-q softmax
// reduction = 2 shuffles (lanes sharing lane&15). P through LDS to B-frag
// layout; PV as O^T_c = mfma(A=V^T chunk, B=P^T). Online softmax state per q.
__global__ __launch_bounds__(64) void attn_kernel(const u16* __restrict__ Q,
                                                  const u16* __restrict__ Kc,
                                                  const u16* __restrict__ Vc,
                                                  u16* __restrict__ Y) {
    __shared__ __align__(16) u16 V_lds[32][68];  // pad 4: 2-way banks on reads
    __shared__ __align__(16) u16 P_lds[32][18];
    __shared__ __align__(16) u16 O_lds[16][64];
    const int lane = threadIdx.x;
    const int lg = lane >> 4, lr = lane & 15;
    const int qb = blockIdx.x * 16;
    const int bh = blockIdx.y;
    const u16* Qb = Q + ((size_t)bh * 1024 + qb) * 64;
    const u16* Kb = Kc + (size_t)bh * 1024 * 64;
    const u16* Vb = Vc + (size_t)bh * 1024 * 64;
    bf16x8 qf0 = *(const bf16x8*)&Qb[lr * 64 + lg * 8];        // B-frag: n=q, k=d
    bf16x8 qf1 = *(const bf16x8*)&Qb[lr * 64 + 32 + lg * 8];
    f32x4 o[4] = {};                                           // O^T chunks
    float m = -1e30f, lsum = 0.f;
    const int i_q = qb + lr;   // this lane's query index (column of S^T)
    const int nkt = qb / 32 + 1;
    for (int kt = 0; kt < nkt; ++kt) {
        const int k0 = kt * 32;
        #pragma unroll
        for (int p = 0; p < 8; ++p) {   // stage V tile [32][64], coalesced
            int row = p * 4 + lg, col = lr * 4;
            *(u16x4*)&V_lds[row][col] = *(const u16x4*)&Vb[(size_t)(k0 + row) * 64 + col];
        }
        f32x4 st[2] = {};
        #pragma unroll
        for (int hh = 0; hh < 2; ++hh) {   // S^T[key 16*hh..][q]
            const u16* Kr = &Kb[(size_t)(k0 + hh * 16 + lr) * 64];
            bf16x8 kf0 = *(const bf16x8*)&Kr[lg * 8];
            bf16x8 kf1 = *(const bf16x8*)&Kr[32 + lg * 8];
            st[hh] = __builtin_amdgcn_mfma_f32_16x16x32_bf16(kf0, qf0, st[hh], 0, 0, 0);
            st[hh] = __builtin_amdgcn_mfma_f32_16x16x32_bf16(kf1, qf1, st[hh], 0, 0, 0);
        }
        float sv[8];
        float tmax = -1e30f;
        #pragma unroll
        for (int hh = 0; hh < 2; ++hh)
            #pragma unroll
            for (int r = 0; r < 4; ++r) {
                int j = k0 + hh * 16 + lg * 4 + r;     // S^T row = key
                float s = (j <= i_q) ? st[hh][r] : -1e30f;
                sv[hh * 4 + r] = s;
                tmax = fmaxf(tmax, s);
            }
        tmax = fmaxf(tmax, __shfl_xor(tmax, 16));
        tmax = fmaxf(tmax, __shfl_xor(tmax, 32));
        float mnew = fmaxf(m, tmax);
        float alpha = __expf(m - mnew);
        float psum = 0.f;
        #pragma unroll
        for (int i = 0; i < 8; ++i) {
            float p = __expf(sv[i] - mnew);
            psum += p;
            int key = (i >> 2) * 16 + lg * 4 + (i & 3);
            P_lds[key][lr] = f2bf(p);
        }
        psum += __shfl_xor(psum, 16);
        psum += __shfl_xor(psum, 32);
        lsum = lsum * alpha + psum;
        m = mnew;
        #pragma unroll
        for (int c = 0; c < 4; ++c) {
            o[c][0] *= alpha; o[c][1] *= alpha; o[c][2] *= alpha; o[c][3] *= alpha;
        }
        __syncthreads();
        u16x8 pt;
        #pragma unroll
        for (int e = 0; e < 8; ++e) pt[e] = P_lds[lg * 8 + e][lr];   // B-frag P^T
        bf16x8 pf = __builtin_bit_cast(bf16x8, pt);
        #pragma unroll
        for (int c = 0; c < 4; ++c) {
            u16x8 vt;
            #pragma unroll
            for (int e = 0; e < 8; ++e) vt[e] = V_lds[lg * 8 + e][c * 16 + lr]; // A-frag V^T
            bf16x8 vf = __builtin_bit_cast(bf16x8, vt);
            o[c] = __builtin_amdgcn_mfma_f32_16x16x32_bf16(vf, pf, o[c], 0, 0, 0);
        }
        __syncthreads();
    }
    float inv = 1.0f / lsum;
    #pragma unroll
    for (int c = 0; c < 4; ++c)
        #pragma unroll
        for (int r = 0; r < 4; ++r)
            O_lds[lr][c * 16 + lg * 4 + r] = f2bf(o[c][r] * inv);
    __syncthreads();
    const int b = bh >> 4, h = bh & 15;
    const int row = lane >> 2, c16 = (lane & 3) * 16;
    size_t g = ((size_t)(b * 1024 + qb + row)) * 1024 + h * 64 + c16;
    *(u16x8*)&Y[g] = *(const u16x8*)&O_lds[row][c16];
    *(u16x8*)&Y[g + 8] = *(const u16x8*)&O_lds[row][c16 + 8];
}

// ---------------------------------------------------------------------------
extern "C" void kernel_launch(void* const* d_in, const int* in_sizes, int n_in,
                              void* d_out, int out_size, void* d_ws, size_t ws_size,
                              hipStream_t stream) {
    const float* x            = (const float*)d_in[0];
    const float* mem_k1       = (const float*)d_in[1];
    const float* mem_v1       = (const float*)d_in[2];
    const float* mem_k2       = (const float*)d_in[3];
    const float* mem_v2       = (const float*)d_in[4];
    const float* mem_k3       = (const float*)d_in[5];
    const float* mem_v3       = (const float*)d_in[6];
    const float* c_attn_w     = (const float*)d_in[7];
    const float* c_attn_b     = (const float*)d_in[8];
    const float* c_proj_w     = (const float*)d_in[9];
    const float* c_proj_b     = (const float*)d_in[10];
    const float* compress_k_w = (const float*)d_in[11];
    const float* ln_k_g       = (const float*)d_in[12];
    const float* ln_k_b       = (const float*)d_in[13];
    const float* compress_v_w = (const float*)d_in[14];
    const float* ln_v_g       = (const float*)d_in[15];
    const float* ln_v_b       = (const float*)d_in[16];

    char* ws = (char*)d_ws;
    u16* x_bf  = (u16*)(ws);                      // [4096][1024]      8 MB
    u16* wq_bf = (u16*)(ws + (8u << 20));         // [3072][1024]      6 MB
    u16* wp_bf = (u16*)(ws + (14u << 20));        // [1024][1024]      2 MB
    u16* q_buf = (u16*)(ws + (16u << 20));        // [64][1024][64]    8 MB
    u16* all_k = (u16*)(ws + (24u << 20));        // [64][1024][64]    8 MB
    u16* all_v = (u16*)(ws + (32u << 20));        // [64][1024][64]    8 MB
    u16* att_y = (u16*)(ws + (40u << 20));        // [4096][1024]      8 MB
    float* out = (float*)d_out;

    cvt_f32_bf16<<<4096, 256, 0, stream>>>(x, x_bf, 1048576);
    cvt_f32_bf16<<<3072, 256, 0, stream>>>(c_attn_w, wq_bf, 786432);
    cvt_f32_bf16<<<1024, 256, 0, stream>>>(c_proj_w, wp_bf, 262144);

    copy_mem_rows<<<dim3(129, 64), 64, 0, stream>>>(mem_k1, all_k, 129, 0);
    copy_mem_rows<<<dim3(129, 64), 64, 0, stream>>>(mem_v1, all_v, 129, 0);
    copy_mem_rows<<<dim3(257, 64), 64, 0, stream>>>(mem_k2, all_k, 257, 129);
    copy_mem_rows<<<dim3(257, 64), 64, 0, stream>>>(mem_v2, all_v, 257, 129);

    compress_ln<<<dim3(257, 64), 64, 0, stream>>>(mem_k3, compress_k_w, ln_k_g, ln_k_b, all_k, 386);
    compress_ln<<<dim3(257, 64), 64, 0, stream>>>(mem_v3, compress_v_w, ln_v_g, ln_v_b, all_v, 386);

    gemm_bt<<<dim3(64, 48), 256, 0, stream>>>(x_bf, wq_bf, c_attn_b, 1024, 3072, 1,
                                              nullptr, q_buf, all_k, all_v);

    attn_kernel<<<dim3(64, 64), 64, 0, stream>>>(q_buf, all_k, all_v, att_y);

    gemm_bt<<<dim3(64, 16), 256, 0, stream>>>(att_y, wp_bf, c_proj_b, 1024, 1024, 0,
                                              out, nullptr, nullptr, nullptr);
}